// Round 5
// baseline (78.561 us; speedup 1.0000x reference)
//
#include <hip/hip_runtime.h>

static constexpr int S_SYS   = 8;
static constexpr int E_PAIRS = 1000000;
static constexpr int N_A     = 20000;
static constexpr int NBINS   = 16;
static constexpr int BPS_MAX = 64;        // partials per system (cap)
static constexpr int BLK     = 256;
static constexpr int UNR     = 4;         // quad-groups in flight per thread

// Kernel 1: per-block LDS-privatized coords (80 KB, 2 blocks/CU), ds_add_f32
// accumulation, plain coalesced partial store. Inner loop issues 4 interleaved
// quad-groups' loads (12 float4 + 4 int4) before any use -> 16 VMEM in flight
// per wave to saturate the miss queue.
__global__ __launch_bounds__(BLK, 2) void coord_lds(
    const float* __restrict__ vec, const int* __restrict__ atom,
    float* __restrict__ partial, int bps)
{
    __shared__ __align__(16) float lc[N_A];          // 80 KB
    for (int i = threadIdx.x; i < N_A; i += BLK) lc[i] = 0.0f;
    __syncthreads();

    const int s = blockIdx.y;
    const int Q = E_PAIRS / 4;                        // 250,000 quad-groups/system
    const float4* vb = reinterpret_cast<const float4*>(vec) + (size_t)s * Q * 3;
    const int4*   ib = reinterpret_cast<const int4*>(atom) + (size_t)s * Q;

    const int W = bps * BLK;                          // lane-contiguous group stride
    for (int t = blockIdx.x * BLK + threadIdx.x; t < Q; t += W * UNR) {
        float4 A[UNR], B[UNR], C[UNR];
        int4   id[UNR];
        bool   ok[UNR];
        #pragma unroll
        for (int u = 0; u < UNR; ++u) {
            int tq = t + u * W;
            ok[u] = (tq < Q);
            if (ok[u]) {
                A[u] = vb[3 * tq];
                B[u] = vb[3 * tq + 1];
                C[u] = vb[3 * tq + 2];
                id[u] = ib[tq];
            }
        }
        #pragma unroll
        for (int u = 0; u < UNR; ++u) {
            if (!ok[u]) continue;
            float px[4] = {A[u].x, A[u].w, B[u].z, C[u].y};
            float py[4] = {A[u].y, B[u].x, B[u].w, C[u].z};
            float pz[4] = {A[u].z, B[u].y, C[u].x, C[u].w};
            int ids[4]  = {id[u].x, id[u].y, id[u].z, id[u].w};
            #pragma unroll
            for (int j = 0; j < 4; ++j) {
                float d = sqrtf(px[j]*px[j] + py[j]*py[j] + pz[j]*pz[j]);
                float y = (d - 4.4f) / 1.1f;          // (d - R1) / (R0 - R1)
                float z;
                if (y <= 0.0f)      z = 1.0f;
                else if (y >= 1.0f) z = 0.0f;
                else { float u2 = y - 1.0f; z = u2 * u2 * (1.0f + 2.0f * y); }
                if (z != 0.0f) atomicAdd(&lc[ids[j]], z);   // ds_add_f32, on-CU
            }
        }
    }
    __syncthreads();

    float4* po = reinterpret_cast<float4*>(partial + ((size_t)s * bps + blockIdx.x) * N_A);
    const float4* ls = reinterpret_cast<const float4*>(lc);
    for (int i = threadIdx.x; i < N_A / 4; i += BLK) po[i] = ls[i];
}

// ---------------- Fallback path (ws too small): global-atomic scatter --------
__global__ __launch_bounds__(256) void coord_scatter(
    const float* __restrict__ vec, const int* __restrict__ atom,
    float* __restrict__ coords)
{
    const int P4 = S_SYS * E_PAIRS / 4;
    int stride = gridDim.x * blockDim.x;
    for (int t = blockIdx.x * blockDim.x + threadIdx.x; t < P4; t += stride) {
        const float4* v4 = reinterpret_cast<const float4*>(vec) + 3ull * (unsigned)t;
        float4 A = v4[0], B = v4[1], C = v4[2];
        int4 id = reinterpret_cast<const int4*>(atom)[t];
        int s = (t * 4) / E_PAIRS;
        float* cs = coords + s * N_A;
        float px[4] = {A.x, A.w, B.z, C.y};
        float py[4] = {A.y, B.x, B.w, C.z};
        float pz[4] = {A.z, B.y, C.x, C.w};
        int ids[4]  = {id.x, id.y, id.z, id.w};
        #pragma unroll
        for (int j = 0; j < 4; ++j) {
            float d = sqrtf(px[j]*px[j] + py[j]*py[j] + pz[j]*pz[j]);
            float y = (d - 4.4f) / 1.1f;
            float z;
            if (y <= 0.0f)      z = 1.0f;
            else if (y >= 1.0f) z = 0.0f;
            else { float u = y - 1.0f; z = u * u * (1.0f + 2.0f * y); }
            if (z != 0.0f) unsafeAtomicAdd(&cs[ids[j]], z);
        }
    }
}

// Kernel 2: sum bps partials per atom, then KDE onto 16 bins.
__global__ __launch_bounds__(256) void kde_reduce(
    const float* __restrict__ partial, float* __restrict__ out, int bps)
{
    int s = blockIdx.y;
    int a = blockIdx.x * 256 + threadIdx.x;
    bool valid = (a < N_A);

    float c = 0.0f;
    if (valid) {
        const float* p = partial + (size_t)s * bps * N_A + a;
        for (int b = 0; b < bps; ++b) c += p[(size_t)b * N_A];
    }

    float vals[NBINS];
    #pragma unroll
    for (int k = 0; k < NBINS; ++k) {
        float d = c - (float)k;
        vals[k] = valid ? expf(-2.0f * d * d) : 0.0f;  // 0.5/SIGMA2 == 2
    }

    #pragma unroll
    for (int k = 0; k < NBINS; ++k) {
        #pragma unroll
        for (int off = 32; off > 0; off >>= 1)
            vals[k] += __shfl_down(vals[k], off, 64);
    }

    __shared__ float sbin[4][NBINS];
    int wave = threadIdx.x >> 6;
    int lane = threadIdx.x & 63;
    if (lane == 0) {
        #pragma unroll
        for (int k = 0; k < NBINS; ++k) sbin[wave][k] = vals[k];
    }
    __syncthreads();
    if (threadIdx.x < NBINS) {
        float v = sbin[0][threadIdx.x] + sbin[1][threadIdx.x]
                + sbin[2][threadIdx.x] + sbin[3][threadIdx.x];
        unsafeAtomicAdd(&out[s * NBINS + threadIdx.x], v);
    }
}

extern "C" void kernel_launch(void* const* d_in, const int* in_sizes, int n_in,
                              void* d_out, int out_size, void* d_ws, size_t ws_size,
                              hipStream_t stream) {
    const float* vec  = (const float*)d_in[0];   // [S,E,3] f32
    const int*   atom = (const int*)d_in[1];     // [S,E] i32
    float* out = (float*)d_out;                  // [S,16] f32
    float* ws  = (float*)d_ws;

    hipMemsetAsync(out, 0, (size_t)S_SYS * NBINS * sizeof(float), stream);

    int bps = (int)(ws_size / ((size_t)S_SYS * N_A * sizeof(float)));
    if (bps > BPS_MAX) bps = BPS_MAX;

    dim3 g2((N_A + 255) / 256, S_SYS);

    if (bps >= 4) {
        dim3 g1(bps, S_SYS);
        coord_lds<<<g1, BLK, 0, stream>>>(vec, atom, ws, bps);
        kde_reduce<<<g2, 256, 0, stream>>>(ws, out, bps);
    } else {
        hipMemsetAsync(ws, 0, (size_t)S_SYS * N_A * sizeof(float), stream);
        coord_scatter<<<2048, 256, 0, stream>>>(vec, atom, ws);
        kde_reduce<<<g2, 256, 0, stream>>>(ws, out, 1);
    }
}

// Round 6
// 72.774 us; speedup vs baseline: 1.0795x; 1.0795x over previous
//
#include <hip/hip_runtime.h>

static constexpr int S_SYS   = 8;
static constexpr int E_PAIRS = 1000000;
static constexpr int N_A     = 20000;
static constexpr int NBINS   = 16;

static constexpr int BPS     = 32;                    // blocks per system (256 blocks = 1/CU)
static constexpr int TILE_P  = 2000;                  // pairs per tile (divides E exactly)
static constexpr int NTILES  = E_PAIRS / TILE_P;      // 500
static constexpr int VEC_CH  = TILE_P * 12 / 16;      // 1500 16B chunks
static constexpr int IDX_CH  = TILE_P * 4  / 16;      // 500
static constexpr int VEC_GRP = (VEC_CH + 63) / 64;    // 24 wave-groups
static constexpr int IDX_GRP = (IDX_CH + 63) / 64;    // 8
static constexpr int STG_VEC = VEC_GRP * 1024;        // 24576 B
static constexpr int STG_IDX = IDX_GRP * 1024;        // 8192 B
static constexpr int STG_B   = STG_VEC + STG_IDX;     // 32768 B per buffer

__device__ __forceinline__ void dma16(const void* g, void* l) {
    __builtin_amdgcn_global_load_lds(
        (const __attribute__((address_space(1))) void*)g,
        (__attribute__((address_space(3)))       void*)l, 16, 0, 0);
}

// Stage one tile: every wave issues exactly 2 global_load_lds (1KB each).
// Waves 0..15 take vec groups 0..15; waves 0..7 also vec groups 16..23;
// waves 8..15 take idx groups 0..7. Partial tail groups clamp the per-lane
// source chunk (duplicate reads land in unread LDS slots).
__device__ __forceinline__ void stage_tile(const char* vsrc, const char* isrc,
                                           char* stg, int w, int lane) {
    {
        int c = w * 64 + lane; if (c > VEC_CH - 1) c = VEC_CH - 1;
        dma16(vsrc + (size_t)c * 16, stg + w * 1024);
    }
    if (w < 8) {
        int g = 16 + w;
        int c = g * 64 + lane; if (c > VEC_CH - 1) c = VEC_CH - 1;
        dma16(vsrc + (size_t)c * 16, stg + g * 1024);
    } else {
        int g = w - 8;
        int c = g * 64 + lane; if (c > IDX_CH - 1) c = IDX_CH - 1;
        dma16(isrc + (size_t)c * 16, stg + STG_VEC + g * 1024);
    }
}

// Kernel 1: dense global_load_lds tile staging (double-buffered, counted
// vmcnt(2), raw s_barrier) + LDS-read compute + ds_add into 80KB private lc.
// 1024 threads, 1 block/CU, LDS = 80000 + 2*32768 = 145536 B.
__global__ __launch_bounds__(1024, 4) void coord_tile(
    const float* __restrict__ vec, const int* __restrict__ atom,
    float* __restrict__ partial)
{
    __shared__ float lc[N_A];                         // 80 KB private coords
    __shared__ __align__(16) char stg[2][STG_B];      // 2 x 32 KB staging

    for (int i = threadIdx.x; i < N_A; i += 1024) lc[i] = 0.0f;
    __syncthreads();                                  // lc zeroed before any ds_add

    const int s = blockIdx.y;
    const int b = blockIdx.x;
    const int w = threadIdx.x >> 6, lane = threadIdx.x & 63;
    const char* vbase = (const char*)(vec + (size_t)s * E_PAIRS * 3);
    const char* ibase = (const char*)(atom + (size_t)s * E_PAIRS);

    const int nt = (NTILES - 1 - b) / BPS + 1;        // tiles for this block (15 or 16)

    // prologue: stage tile index b into buf 0
    stage_tile(vbase + (size_t)b * TILE_P * 12, ibase + (size_t)b * TILE_P * 4,
               stg[0], w, lane);

    for (int t = 0; t < nt; ++t) {
        const int p = t & 1;
        if (t + 1 < nt) {
            int tt = b + (t + 1) * BPS;
            stage_tile(vbase + (size_t)tt * TILE_P * 12, ibase + (size_t)tt * TILE_P * 4,
                       stg[p ^ 1], w, lane);
            asm volatile("s_waitcnt vmcnt(2)" ::: "memory");  // tile t landed, t+1 in flight
        } else {
            asm volatile("s_waitcnt vmcnt(0)" ::: "memory");
        }
        asm volatile("s_barrier" ::: "memory");       // all waves: tile t ready

        const float* sv = (const float*)stg[p];
        const int*   si = (const int*)(stg[p] + STG_VEC);
        #pragma unroll
        for (int r = 0; r < 2; ++r) {
            int pr = (int)threadIdx.x + r * 1024;
            if (pr < TILE_P) {
                float x = sv[3 * pr], y = sv[3 * pr + 1], zc = sv[3 * pr + 2];
                int   id = si[pr];
                float d = sqrtf(x * x + y * y + zc * zc);
                float yy = (d - 4.4f) / 1.1f;         // (d - R1) / (R0 - R1)
                float z;
                if (yy <= 0.0f)      z = 1.0f;
                else if (yy >= 1.0f) z = 0.0f;
                else { float u = yy - 1.0f; z = u * u * (1.0f + 2.0f * yy); }
                if (z != 0.0f) atomicAdd(&lc[id], z); // ds_add_f32
            }
        }
        asm volatile("s_barrier" ::: "memory");       // buf p free for overwrite
    }
    __syncthreads();                                  // drain ds_adds

    float4* po = (float4*)(partial + ((size_t)s * BPS + b) * N_A);
    const float4* ls = (const float4*)lc;
    for (int i = threadIdx.x; i < N_A / 4; i += 1024) po[i] = ls[i];
}

// ---------------- Fallback path (ws too small): global-atomic scatter --------
__global__ __launch_bounds__(256) void coord_scatter(
    const float* __restrict__ vec, const int* __restrict__ atom,
    float* __restrict__ coords)
{
    const int P4 = S_SYS * E_PAIRS / 4;
    int stride = gridDim.x * blockDim.x;
    for (int t = blockIdx.x * blockDim.x + threadIdx.x; t < P4; t += stride) {
        const float4* v4 = reinterpret_cast<const float4*>(vec) + 3ull * (unsigned)t;
        float4 A = v4[0], B = v4[1], C = v4[2];
        int4 id = reinterpret_cast<const int4*>(atom)[t];
        int s = (t * 4) / E_PAIRS;
        float* cs = coords + s * N_A;
        float px[4] = {A.x, A.w, B.z, C.y};
        float py[4] = {A.y, B.x, B.w, C.z};
        float pz[4] = {A.z, B.y, C.x, C.w};
        int ids[4]  = {id.x, id.y, id.z, id.w};
        #pragma unroll
        for (int j = 0; j < 4; ++j) {
            float d = sqrtf(px[j]*px[j] + py[j]*py[j] + pz[j]*pz[j]);
            float y = (d - 4.4f) / 1.1f;
            float z;
            if (y <= 0.0f)      z = 1.0f;
            else if (y >= 1.0f) z = 0.0f;
            else { float u = y - 1.0f; z = u * u * (1.0f + 2.0f * y); }
            if (z != 0.0f) unsafeAtomicAdd(&cs[ids[j]], z);
        }
    }
}

// Kernel 2: sum bps partials per atom, then KDE onto 16 bins.
__global__ __launch_bounds__(256) void kde_reduce(
    const float* __restrict__ partial, float* __restrict__ out, int bps)
{
    int s = blockIdx.y;
    int a = blockIdx.x * 256 + threadIdx.x;
    bool valid = (a < N_A);

    float c = 0.0f;
    if (valid) {
        const float* p = partial + (size_t)s * bps * N_A + a;
        for (int b = 0; b < bps; ++b) c += p[(size_t)b * N_A];
    }

    float vals[NBINS];
    #pragma unroll
    for (int k = 0; k < NBINS; ++k) {
        float d = c - (float)k;
        vals[k] = valid ? expf(-2.0f * d * d) : 0.0f;  // 0.5/SIGMA2 == 2
    }

    #pragma unroll
    for (int k = 0; k < NBINS; ++k) {
        #pragma unroll
        for (int off = 32; off > 0; off >>= 1)
            vals[k] += __shfl_down(vals[k], off, 64);
    }

    __shared__ float sbin[4][NBINS];
    int wave = threadIdx.x >> 6;
    int lane = threadIdx.x & 63;
    if (lane == 0) {
        #pragma unroll
        for (int k = 0; k < NBINS; ++k) sbin[wave][k] = vals[k];
    }
    __syncthreads();
    if (threadIdx.x < NBINS) {
        float v = sbin[0][threadIdx.x] + sbin[1][threadIdx.x]
                + sbin[2][threadIdx.x] + sbin[3][threadIdx.x];
        unsafeAtomicAdd(&out[s * NBINS + threadIdx.x], v);
    }
}

extern "C" void kernel_launch(void* const* d_in, const int* in_sizes, int n_in,
                              void* d_out, int out_size, void* d_ws, size_t ws_size,
                              hipStream_t stream) {
    const float* vec  = (const float*)d_in[0];   // [S,E,3] f32
    const int*   atom = (const int*)d_in[1];     // [S,E] i32
    float* out = (float*)d_out;                  // [S,16] f32
    float* ws  = (float*)d_ws;

    hipMemsetAsync(out, 0, (size_t)S_SYS * NBINS * sizeof(float), stream);

    const size_t need = (size_t)S_SYS * BPS * N_A * sizeof(float);   // 20.5 MB
    dim3 g2((N_A + 255) / 256, S_SYS);

    if (ws_size >= need) {
        dim3 g1(BPS, S_SYS);                      // 256 blocks = 1/CU
        coord_tile<<<g1, 1024, 0, stream>>>(vec, atom, ws);
        kde_reduce<<<g2, 256, 0, stream>>>(ws, out, BPS);
    } else {
        hipMemsetAsync(ws, 0, (size_t)S_SYS * N_A * sizeof(float), stream);
        coord_scatter<<<2048, 256, 0, stream>>>(vec, atom, ws);
        kde_reduce<<<g2, 256, 0, stream>>>(ws, out, 1);
    }
}

// Round 7
// 51.640 us; speedup vs baseline: 1.5213x; 1.4093x over previous
//
#include <hip/hip_runtime.h>

static constexpr int S_SYS   = 8;
static constexpr int E_PAIRS = 1000000;
static constexpr int N_A     = 20000;
static constexpr int NBINS   = 16;
static constexpr int BPS_MAX = 64;
static constexpr int BLK     = 1024;
static constexpr float SCALE   = 4194304.0f;       // 2^22
static constexpr float INV_SCL = 1.0f / 4194304.0f;

// Kernel 1: LDS-privatized coords as u32 fixed-point (2^22). ds_add_u32 is the
// single variable changed vs the 57us float version: testing whether gfx950's
// LDS fp-atomic path is the serialized invariant cost.
__global__ __launch_bounds__(BLK, 8) void coord_lds_u32(
    const float* __restrict__ vec, const int* __restrict__ atom,
    unsigned* __restrict__ partial, int bps)
{
    __shared__ __align__(16) unsigned lc[N_A];        // 80 KB
    for (int i = threadIdx.x; i < N_A; i += BLK) lc[i] = 0u;
    __syncthreads();

    const int s = blockIdx.y;
    const int Q = E_PAIRS / 4;                        // 250,000 quad-groups/system
    const float4* vb = reinterpret_cast<const float4*>(vec) + (size_t)s * Q * 3;
    const int4*   ib = reinterpret_cast<const int4*>(atom) + (size_t)s * Q;

    const int stride = bps * BLK;
    for (int t = blockIdx.x * BLK + threadIdx.x; t < Q; t += stride) {
        float4 A = vb[3 * t], B = vb[3 * t + 1], C = vb[3 * t + 2];
        int4 id = ib[t];

        float px[4] = {A.x, A.w, B.z, C.y};
        float py[4] = {A.y, B.x, B.w, C.z};
        float pz[4] = {A.z, B.y, C.x, C.w};
        int ids[4]  = {id.x, id.y, id.z, id.w};

        #pragma unroll
        for (int j = 0; j < 4; ++j) {
            float d = sqrtf(px[j]*px[j] + py[j]*py[j] + pz[j]*pz[j]);
            float y = (d - 4.4f) / 1.1f;              // (d - R1) / (R0 - R1)
            float z;
            if (y <= 0.0f)      z = 1.0f;
            else if (y >= 1.0f) z = 0.0f;
            else { float u = y - 1.0f; z = u * u * (1.0f + 2.0f * y); }
            if (z != 0.0f)
                atomicAdd(&lc[ids[j]], __float2uint_rn(z * SCALE));  // ds_add_u32
        }
    }
    __syncthreads();

    uint4* po = reinterpret_cast<uint4*>(partial + ((size_t)s * bps + blockIdx.x) * N_A);
    const uint4* ls = reinterpret_cast<const uint4*>(lc);
    for (int i = threadIdx.x; i < N_A / 4; i += BLK) po[i] = ls[i];
}

// Kernel 2 (fast path): exact u32 sum of partials -> float coord -> KDE.
__global__ __launch_bounds__(256) void kde_reduce_u32(
    const unsigned* __restrict__ partial, float* __restrict__ out, int bps)
{
    int s = blockIdx.y;
    int a = blockIdx.x * 256 + threadIdx.x;
    bool valid = (a < N_A);

    unsigned acc = 0u;
    if (valid) {
        const unsigned* p = partial + (size_t)s * bps * N_A + a;
        for (int b = 0; b < bps; ++b) acc += p[(size_t)b * N_A];
    }
    float c = (float)acc * INV_SCL;

    float vals[NBINS];
    #pragma unroll
    for (int k = 0; k < NBINS; ++k) {
        float d = c - (float)k;
        vals[k] = valid ? expf(-2.0f * d * d) : 0.0f;  // 0.5/SIGMA2 == 2
    }

    #pragma unroll
    for (int k = 0; k < NBINS; ++k) {
        #pragma unroll
        for (int off = 32; off > 0; off >>= 1)
            vals[k] += __shfl_down(vals[k], off, 64);
    }

    __shared__ float sbin[4][NBINS];
    int wave = threadIdx.x >> 6;
    int lane = threadIdx.x & 63;
    if (lane == 0) {
        #pragma unroll
        for (int k = 0; k < NBINS; ++k) sbin[wave][k] = vals[k];
    }
    __syncthreads();
    if (threadIdx.x < NBINS) {
        float v = sbin[0][threadIdx.x] + sbin[1][threadIdx.x]
                + sbin[2][threadIdx.x] + sbin[3][threadIdx.x];
        unsafeAtomicAdd(&out[s * NBINS + threadIdx.x], v);
    }
}

// ---------------- Fallback path (ws too small): global-atomic scatter --------
__global__ __launch_bounds__(256) void coord_scatter(
    const float* __restrict__ vec, const int* __restrict__ atom,
    float* __restrict__ coords)
{
    const int P4 = S_SYS * E_PAIRS / 4;
    int stride = gridDim.x * blockDim.x;
    for (int t = blockIdx.x * blockDim.x + threadIdx.x; t < P4; t += stride) {
        const float4* v4 = reinterpret_cast<const float4*>(vec) + 3ull * (unsigned)t;
        float4 A = v4[0], B = v4[1], C = v4[2];
        int4 id = reinterpret_cast<const int4*>(atom)[t];
        int s = (t * 4) / E_PAIRS;
        float* cs = coords + s * N_A;
        float px[4] = {A.x, A.w, B.z, C.y};
        float py[4] = {A.y, B.x, B.w, C.z};
        float pz[4] = {A.z, B.y, C.x, C.w};
        int ids[4]  = {id.x, id.y, id.z, id.w};
        #pragma unroll
        for (int j = 0; j < 4; ++j) {
            float d = sqrtf(px[j]*px[j] + py[j]*py[j] + pz[j]*pz[j]);
            float y = (d - 4.4f) / 1.1f;
            float z;
            if (y <= 0.0f)      z = 1.0f;
            else if (y >= 1.0f) z = 0.0f;
            else { float u = y - 1.0f; z = u * u * (1.0f + 2.0f * y); }
            if (z != 0.0f) unsafeAtomicAdd(&cs[ids[j]], z);
        }
    }
}

__global__ __launch_bounds__(256) void kde_reduce_f32(
    const float* __restrict__ coords, float* __restrict__ out)
{
    int s = blockIdx.y;
    int a = blockIdx.x * 256 + threadIdx.x;
    bool valid = (a < N_A);
    float c = valid ? coords[(size_t)s * N_A + a] : 0.0f;

    float vals[NBINS];
    #pragma unroll
    for (int k = 0; k < NBINS; ++k) {
        float d = c - (float)k;
        vals[k] = valid ? expf(-2.0f * d * d) : 0.0f;
    }
    #pragma unroll
    for (int k = 0; k < NBINS; ++k) {
        #pragma unroll
        for (int off = 32; off > 0; off >>= 1)
            vals[k] += __shfl_down(vals[k], off, 64);
    }
    __shared__ float sbin[4][NBINS];
    int wave = threadIdx.x >> 6;
    int lane = threadIdx.x & 63;
    if (lane == 0) {
        #pragma unroll
        for (int k = 0; k < NBINS; ++k) sbin[wave][k] = vals[k];
    }
    __syncthreads();
    if (threadIdx.x < NBINS) {
        float v = sbin[0][threadIdx.x] + sbin[1][threadIdx.x]
                + sbin[2][threadIdx.x] + sbin[3][threadIdx.x];
        unsafeAtomicAdd(&out[s * NBINS + threadIdx.x], v);
    }
}

extern "C" void kernel_launch(void* const* d_in, const int* in_sizes, int n_in,
                              void* d_out, int out_size, void* d_ws, size_t ws_size,
                              hipStream_t stream) {
    const float* vec  = (const float*)d_in[0];   // [S,E,3] f32
    const int*   atom = (const int*)d_in[1];     // [S,E] i32
    float* out = (float*)d_out;                  // [S,16] f32

    hipMemsetAsync(out, 0, (size_t)S_SYS * NBINS * sizeof(float), stream);

    int bps = (int)(ws_size / ((size_t)S_SYS * N_A * sizeof(unsigned)));
    if (bps > BPS_MAX) bps = BPS_MAX;

    dim3 g2((N_A + 255) / 256, S_SYS);

    if (bps >= 4) {
        unsigned* ws = (unsigned*)d_ws;
        dim3 g1(bps, S_SYS);
        coord_lds_u32<<<g1, BLK, 0, stream>>>(vec, atom, ws, bps);
        kde_reduce_u32<<<g2, 256, 0, stream>>>(ws, out, bps);
    } else {
        float* ws = (float*)d_ws;
        hipMemsetAsync(ws, 0, (size_t)S_SYS * N_A * sizeof(float), stream);
        coord_scatter<<<2048, 256, 0, stream>>>(vec, atom, ws);
        kde_reduce_f32<<<g2, 256, 0, stream>>>(ws, out);
    }
}

// Round 8
// 42.605 us; speedup vs baseline: 1.8439x; 1.2121x over previous
//
#include <hip/hip_runtime.h>

static constexpr int S_SYS   = 8;
static constexpr int E_PAIRS = 1000000;
static constexpr int N_A     = 20000;
static constexpr int NBINS   = 16;
static constexpr int BPS     = 32;                 // 256 blocks = 1/CU
static constexpr int BLK     = 1024;
static constexpr int UNR     = 2;                  // quad-groups in flight
static constexpr float SCALE   = 4194304.0f;       // 2^22
static constexpr float INV_SCL = 1.0f / 4194304.0f;
static constexpr unsigned ONE_FX = 4194304u;       // z=1.0 in fixed point
static constexpr float QLO = 19.36f;               // 4.4^2  (z==1 below)
static constexpr float QHI = 30.25f;               // 5.5^2  (z==0 above)
static constexpr float INV11 = 1.0f / 1.1f;

// Kernel 1: LDS-privatized u32 fixed-point coords, fire-and-forget ds_add_u32.
// Shell-skip: q=d^2 classified against [4.4^2, 5.5^2] so only ~20% of pairs
// run sqrt+poly; fdiv replaced by *(1/1.1). UNR=2 quad-groups of loads issued
// ahead of use.
__global__ __launch_bounds__(BLK, 4) void coord_lds_u32(
    const float* __restrict__ vec, const int* __restrict__ atom,
    unsigned* __restrict__ partial)
{
    __shared__ __align__(16) unsigned lc[N_A];        // 80 KB
    for (int i = threadIdx.x; i < N_A; i += BLK) lc[i] = 0u;
    __syncthreads();

    const int s = blockIdx.y;
    const int Q = E_PAIRS / 4;                        // 250,000 quad-groups/system
    const float4* vb = reinterpret_cast<const float4*>(vec) + (size_t)s * Q * 3;
    const int4*   ib = reinterpret_cast<const int4*>(atom) + (size_t)s * Q;

    const int W = BPS * BLK;                          // 32768
    for (int t = blockIdx.x * BLK + threadIdx.x; t < Q; t += W * UNR) {
        float4 A[UNR], B[UNR], C[UNR];
        int4   id[UNR];
        bool   ok[UNR];
        #pragma unroll
        for (int u = 0; u < UNR; ++u) {
            int tq = t + u * W;
            ok[u] = (tq < Q);
            if (ok[u]) {
                A[u] = vb[3 * tq]; B[u] = vb[3 * tq + 1]; C[u] = vb[3 * tq + 2];
                id[u] = ib[tq];
            }
        }
        #pragma unroll
        for (int u = 0; u < UNR; ++u) {
            if (!ok[u]) continue;
            float px[4] = {A[u].x, A[u].w, B[u].z, C[u].y};
            float py[4] = {A[u].y, B[u].x, B[u].w, C[u].z};
            float pz[4] = {A[u].z, B[u].y, C[u].x, C[u].w};
            int ids[4]  = {id[u].x, id[u].y, id[u].z, id[u].w};
            #pragma unroll
            for (int j = 0; j < 4; ++j) {
                float q = px[j]*px[j] + py[j]*py[j] + pz[j]*pz[j];
                if (q < QLO) {
                    atomicAdd(&lc[ids[j]], ONE_FX);           // z == 1
                } else if (q < QHI) {                         // switching shell
                    float d = sqrtf(q);
                    float y = (d - 4.4f) * INV11;
                    float uu = y - 1.0f;
                    float z = uu * uu * (1.0f + 2.0f * y);
                    unsigned fx = __float2uint_rn(z * SCALE);
                    if (fx) atomicAdd(&lc[ids[j]], fx);       // ds_add_u32
                }                                             // else z == 0
            }
        }
    }
    __syncthreads();

    uint4* po = reinterpret_cast<uint4*>(partial + ((size_t)s * BPS + blockIdx.x) * N_A);
    const uint4* ls = reinterpret_cast<const uint4*>(lc);
    for (int i = threadIdx.x; i < N_A / 4; i += BLK) po[i] = ls[i];
}

// Kernel 2 (fast path): exact u32 sum of partials -> float coord -> KDE.
__global__ __launch_bounds__(256) void kde_reduce_u32(
    const unsigned* __restrict__ partial, float* __restrict__ out)
{
    int s = blockIdx.y;
    int a = blockIdx.x * 256 + threadIdx.x;
    bool valid = (a < N_A);

    unsigned acc = 0u;
    if (valid) {
        const unsigned* p = partial + (size_t)s * BPS * N_A + a;
        #pragma unroll 8
        for (int b = 0; b < BPS; ++b) acc += p[(size_t)b * N_A];
    }
    float c = (float)acc * INV_SCL;

    float vals[NBINS];
    #pragma unroll
    for (int k = 0; k < NBINS; ++k) {
        float d = c - (float)k;
        vals[k] = valid ? expf(-2.0f * d * d) : 0.0f;  // 0.5/SIGMA2 == 2
    }

    #pragma unroll
    for (int k = 0; k < NBINS; ++k) {
        #pragma unroll
        for (int off = 32; off > 0; off >>= 1)
            vals[k] += __shfl_down(vals[k], off, 64);
    }

    __shared__ float sbin[4][NBINS];
    int wave = threadIdx.x >> 6;
    int lane = threadIdx.x & 63;
    if (lane == 0) {
        #pragma unroll
        for (int k = 0; k < NBINS; ++k) sbin[wave][k] = vals[k];
    }
    __syncthreads();
    if (threadIdx.x < NBINS) {
        float v = sbin[0][threadIdx.x] + sbin[1][threadIdx.x]
                + sbin[2][threadIdx.x] + sbin[3][threadIdx.x];
        unsafeAtomicAdd(&out[s * NBINS + threadIdx.x], v);
    }
}

// ---------------- Fallback path (ws too small): global-atomic scatter --------
__global__ __launch_bounds__(256) void coord_scatter(
    const float* __restrict__ vec, const int* __restrict__ atom,
    float* __restrict__ coords)
{
    const int P4 = S_SYS * E_PAIRS / 4;
    int stride = gridDim.x * blockDim.x;
    for (int t = blockIdx.x * blockDim.x + threadIdx.x; t < P4; t += stride) {
        const float4* v4 = reinterpret_cast<const float4*>(vec) + 3ull * (unsigned)t;
        float4 A = v4[0], B = v4[1], C = v4[2];
        int4 id = reinterpret_cast<const int4*>(atom)[t];
        int s = (t * 4) / E_PAIRS;
        float* cs = coords + s * N_A;
        float px[4] = {A.x, A.w, B.z, C.y};
        float py[4] = {A.y, B.x, B.w, C.z};
        float pz[4] = {A.z, B.y, C.x, C.w};
        int ids[4]  = {id.x, id.y, id.z, id.w};
        #pragma unroll
        for (int j = 0; j < 4; ++j) {
            float d = sqrtf(px[j]*px[j] + py[j]*py[j] + pz[j]*pz[j]);
            float y = (d - 4.4f) / 1.1f;
            float z;
            if (y <= 0.0f)      z = 1.0f;
            else if (y >= 1.0f) z = 0.0f;
            else { float u = y - 1.0f; z = u * u * (1.0f + 2.0f * y); }
            if (z != 0.0f) unsafeAtomicAdd(&cs[ids[j]], z);
        }
    }
}

__global__ __launch_bounds__(256) void kde_reduce_f32(
    const float* __restrict__ coords, float* __restrict__ out)
{
    int s = blockIdx.y;
    int a = blockIdx.x * 256 + threadIdx.x;
    bool valid = (a < N_A);
    float c = valid ? coords[(size_t)s * N_A + a] : 0.0f;

    float vals[NBINS];
    #pragma unroll
    for (int k = 0; k < NBINS; ++k) {
        float d = c - (float)k;
        vals[k] = valid ? expf(-2.0f * d * d) : 0.0f;
    }
    #pragma unroll
    for (int k = 0; k < NBINS; ++k) {
        #pragma unroll
        for (int off = 32; off > 0; off >>= 1)
            vals[k] += __shfl_down(vals[k], off, 64);
    }
    __shared__ float sbin[4][NBINS];
    int wave = threadIdx.x >> 6;
    int lane = threadIdx.x & 63;
    if (lane == 0) {
        #pragma unroll
        for (int k = 0; k < NBINS; ++k) sbin[wave][k] = vals[k];
    }
    __syncthreads();
    if (threadIdx.x < NBINS) {
        float v = sbin[0][threadIdx.x] + sbin[1][threadIdx.x]
                + sbin[2][threadIdx.x] + sbin[3][threadIdx.x];
        unsafeAtomicAdd(&out[s * NBINS + threadIdx.x], v);
    }
}

extern "C" void kernel_launch(void* const* d_in, const int* in_sizes, int n_in,
                              void* d_out, int out_size, void* d_ws, size_t ws_size,
                              hipStream_t stream) {
    const float* vec  = (const float*)d_in[0];   // [S,E,3] f32
    const int*   atom = (const int*)d_in[1];     // [S,E] i32
    float* out = (float*)d_out;                  // [S,16] f32

    hipMemsetAsync(out, 0, (size_t)S_SYS * NBINS * sizeof(float), stream);

    const size_t need = (size_t)S_SYS * BPS * N_A * sizeof(unsigned);  // 20.5 MB
    dim3 g2((N_A + 255) / 256, S_SYS);

    if (ws_size >= need) {
        unsigned* ws = (unsigned*)d_ws;
        dim3 g1(BPS, S_SYS);                      // 256 blocks
        coord_lds_u32<<<g1, BLK, 0, stream>>>(vec, atom, ws);
        kde_reduce_u32<<<g2, 256, 0, stream>>>(ws, out);
    } else {
        float* ws = (float*)d_ws;
        hipMemsetAsync(ws, 0, (size_t)S_SYS * N_A * sizeof(float), stream);
        coord_scatter<<<2048, 256, 0, stream>>>(vec, atom, ws);
        kde_reduce_f32<<<g2, 256, 0, stream>>>(ws, out);
    }
}